// Round 10
// baseline (1731.297 us; speedup 1.0000x reference)
//
#include <hip/hip_runtime.h>

// Bit-exact gold model (VERIFIED rounds 12-13, absmax=0): per C element the
// GEMM is 4 panels of 512 sequential fmaf's (k ascending, single acc); panel
// sums folded ((p0+p1)+p2)+p3; then bias add; elementwise = one rounded fp32
// op per ufunc, contract(off).
// Round 24: P8xQ8 per-lane outer product. Model fit (R6/R7/R9): LDS costs
// ~12 cyc per ds_read_b128 REGARDLESS of broadcast -> minimize LDS instrs
// per MAC: (P+Q)/4 reads per P*Q MACs. Max P=Q=8 under >=4 waves/CU
// (<=64 acc/lane): 4 reads / 64 MACs = 1.5x fewer than R7's 3/32.
// Lane=(mg=lane>>3, ng=lane&7): A = As[kk][mg*8] (8 addr x 8-way bcast,
// 2-way banks = free), B = Bs[kk][w*64+ng*8]. Wave tile 64mx64n, 2-wave
// blocks, grid (16,8,4)=512 = 2 blocks/CU = 4 waves/CU. 2-kk-deep 3-set
// rotation; DMA staging; __syncthreads dbuf. LDS floor ~41 us vs FMA 27.3.

#pragma clang fp contract(off)

#define B_ROWS 512
#define N_OUT 2048
#define K_IN 2048
#define NSTEP 16
#define NPANEL 4
#define PANK 512
#define BKT 16                 // k per tile
#define BTM 64                 // block m rows (8 groups x 8)
#define BTN 128                // block n cols (2 waves x 64)
#define NTILES (PANK / BKT)    // 32

typedef const __attribute__((address_space(1))) void* gptr_t;
typedef __attribute__((address_space(3))) void* lptr_t;

// ---- 32x32 LDS-tiled transpose: WT[k][n] = W[n][k] (*mask) ----
__global__ __launch_bounds__(256) void transpose_tile(
    const float* __restrict__ W, const int* __restrict__ mask,
    float* __restrict__ WT, int useMask)
{
    __shared__ float t[32][33];
    int kb = blockIdx.x * 32, nb = blockIdx.y * 32;
    int tx = threadIdx.x, ty = threadIdx.y;   // block (32, 8)
#pragma unroll
    for (int r = 0; r < 32; r += 8) {
        size_t src = (size_t)(nb + ty + r) * K_IN + (kb + tx);
        float v = W[src];
        if (useMask) v *= (float)mask[src];   // mask in {0,1}: exact
        t[ty + r][tx] = v;
    }
    __syncthreads();
#pragma unroll
    for (int r = 0; r < 32; r += 8)
        WT[(size_t)(kb + ty + r) * N_OUT + (nb + tx)] = t[tx][ty + r];
}

__global__ __launch_bounds__(256) void init_state(float* mem, float* ath,
                                                  float* ssum, float* spk) {
    int idx = blockIdx.x * 256 + threadIdx.x;
    mem[idx] = 0.0f; ath[idx] = 0.0f; ssum[idx] = 0.0f; spk[idx] = 0.0f;
}

// ---- one K-panel of C = A @ BT : Cp[panel][m][n], bit-exact 512-chain ----
// 2 waves/block. Lane (mg,ng) owns rows m0+mg*8..+7, cols n0+w*64+ng*8..+7.
// Per kk: 2 A-reads (8-way broadcast) + 2 B-reads -> 64 FMAs.
__global__ __launch_bounds__(128, 1) void gemm_panel(
    const float* __restrict__ A,    // [512][2048] (x or spk)
    const float* __restrict__ BT,   // [2048][2048] (WT)
    float* __restrict__ Cp)         // [4][512][2048]
{
    __shared__ float Bs[2][BKT][BTN];   // 16 KB
    __shared__ float As[2][BKT][BTM];   //  8 KB
    const int tid  = threadIdx.x;
    const int w    = tid >> 6;          // wave 0..1
    const int lane = tid & 63;
    const int mg   = lane >> 3;         // 0..7
    const int ng   = lane & 7;          // 0..7
    const int n0 = blockIdx.x * BTN;
    const int m0 = blockIdx.y * BTM;
    const int pan = blockIdx.z;
    const int kbase = pan * PANK;

    float acc[8][8];
#pragma unroll
    for (int i = 0; i < 8; i++)
#pragma unroll
        for (int j = 0; j < 8; j++) acc[i][j] = 0.0f;

    // stage(buf, kt): per wave 4 B-DMAs (2 rows each) + 8 A-DMAs (1 k-row).
    //  B: dst base wave-uniform; lane l writes +l*16 -> rows row, row+1.
    //  A: As[k][m], lane l writes As[k][l] = A[m0+l][k'] (stride-K gather).
    auto stage = [&](int buf, int kt) {
#pragma unroll
        for (int i = 0; i < 4; i++) {
            const int row = w * 8 + 2 * i;
            __builtin_amdgcn_global_load_lds(
                (gptr_t)(uintptr_t)(BT + (size_t)(kbase + kt * BKT + row + (lane >> 5)) * N_OUT
                                        + n0 + (lane & 31) * 4),
                (lptr_t)(uintptr_t)&Bs[buf][row][0], 16, 0, 0);
        }
#pragma unroll
        for (int i = 0; i < 8; i++) {
            const int kr = w * 8 + i;
            __builtin_amdgcn_global_load_lds(
                (gptr_t)(uintptr_t)(A + (size_t)(m0 + lane) * K_IN
                                       + kbase + kt * BKT + kr),
                (lptr_t)(uintptr_t)&As[buf][kr][0], 4, 0, 0);
        }
    };

    stage(0, 0);
    for (int kt = 0; kt < NTILES; kt++) {
        const int buf = kt & 1;
        // syncthreads: vmcnt(0)+lgkmcnt(0)+barrier. This wave's DMAs for buf
        // are a full kt old; barrier => all waves' DMAs landed & everyone
        // finished reading buf^1.
        __syncthreads();
        if (kt + 1 < NTILES) stage(buf ^ 1, kt + 1);  // flies during compute

        // 2-kk-deep 3-set rotation (fully unrolled, static indexing).
        float4 av[3][2], bv[3][2];
        av[0][0] = *(const float4*)&As[buf][0][mg * 8];
        av[0][1] = *(const float4*)&As[buf][0][mg * 8 + 4];
        bv[0][0] = *(const float4*)&Bs[buf][0][w * 64 + ng * 8];
        bv[0][1] = *(const float4*)&Bs[buf][0][w * 64 + ng * 8 + 4];
        av[1][0] = *(const float4*)&As[buf][1][mg * 8];
        av[1][1] = *(const float4*)&As[buf][1][mg * 8 + 4];
        bv[1][0] = *(const float4*)&Bs[buf][1][w * 64 + ng * 8];
        bv[1][1] = *(const float4*)&Bs[buf][1][w * 64 + ng * 8 + 4];
#pragma unroll
        for (int kk = 0; kk < BKT; kk++) {
            if (kk + 2 < BKT) {
                const int s = (kk + 2) % 3;
                av[s][0] = *(const float4*)&As[buf][kk + 2][mg * 8];
                av[s][1] = *(const float4*)&As[buf][kk + 2][mg * 8 + 4];
                bv[s][0] = *(const float4*)&Bs[buf][kk + 2][w * 64 + ng * 8];
                bv[s][1] = *(const float4*)&Bs[buf][kk + 2][w * 64 + ng * 8 + 4];
            }
            const int c = kk % 3;
            const float a[8] = {av[c][0].x, av[c][0].y, av[c][0].z, av[c][0].w,
                                av[c][1].x, av[c][1].y, av[c][1].z, av[c][1].w};
            const float b[8] = {bv[c][0].x, bv[c][0].y, bv[c][0].z, bv[c][0].w,
                                bv[c][1].x, bv[c][1].y, bv[c][1].z, bv[c][1].w};
            // kt asc, kk asc, single accumulator => gold 512-chain order
#pragma unroll
            for (int i = 0; i < 8; i++)
#pragma unroll
                for (int j = 0; j < 8; j++)
                    acc[i][j] = fmaf(a[i], b[j], acc[i][j]);
        }
    }

    const size_t P = (size_t)B_ROWS * N_OUT;
#pragma unroll
    for (int i = 0; i < 8; i++) {
        size_t off = (size_t)pan * P
                   + (size_t)(m0 + mg * 8 + i) * N_OUT + n0 + w * 64 + ng * 8;
        *(float4*)(Cp + off)     = make_float4(acc[i][0], acc[i][1], acc[i][2], acc[i][3]);
        *(float4*)(Cp + off + 4) = make_float4(acc[i][4], acc[i][5], acc[i][6], acc[i][7]);
    }
}

// ---- ff = fold(Cp) + b_fc  (bit-exact ordered fold) ----
__global__ __launch_bounds__(256) void ff_fold(
    const float* __restrict__ Cp, const float* __restrict__ b_fc,
    float* __restrict__ ff)
{
    const size_t P = (size_t)B_ROWS * N_OUT;
    size_t base = ((size_t)blockIdx.x * 256 + threadIdx.x) * 4;
    int n = (int)(base & (N_OUT - 1));
    float4 p0 = *(const float4*)(Cp + base);
    float4 p1 = *(const float4*)(Cp + P + base);
    float4 p2 = *(const float4*)(Cp + 2 * P + base);
    float4 p3 = *(const float4*)(Cp + 3 * P + base);
    float4 bv = *(const float4*)(b_fc + n);
    float4 o;
    o.x = (((p0.x + p1.x) + p2.x) + p3.x) + bv.x;
    o.y = (((p0.y + p1.y) + p2.y) + p3.y) + bv.y;
    o.z = (((p0.z + p1.z) + p2.z) + p3.z) + bv.z;
    o.w = (((p0.w + p1.w) + p2.w) + p3.w) + bv.w;
    *(float4*)(ff + base) = o;
}

// ---- fold(Cp) + b_rec -> memr, then fused fp32 SNN elementwise update ----
__global__ __launch_bounds__(256) void fold_update(
    const float* __restrict__ Cp, const float* __restrict__ b_rec,
    const float* __restrict__ spk_in, const float* __restrict__ ff,
    float* __restrict__ mem, float* __restrict__ ath,
    float* __restrict__ ssum, float* __restrict__ spk_out,
    float* __restrict__ out, int last)
{
    const size_t P = (size_t)B_ROWS * N_OUT;
    size_t base = ((size_t)blockIdx.x * 256 + threadIdx.x) * 4;
    int n = (int)(base & (N_OUT - 1));
    float4 p0 = *(const float4*)(Cp + base);
    float4 p1 = *(const float4*)(Cp + P + base);
    float4 p2 = *(const float4*)(Cp + 2 * P + base);
    float4 p3 = *(const float4*)(Cp + 3 * P + base);
    float4 bv = *(const float4*)(b_rec + n);
    float4 sv = *(const float4*)(spk_in + base);
    float4 av = *(const float4*)(ath + base);
    float4 mv = *(const float4*)(mem + base);
    float4 fv = *(const float4*)(ff + base);
    float4 uv = *(const float4*)(ssum + base);

    float cr[4] = {(((p0.x + p1.x) + p2.x) + p3.x),
                   (((p0.y + p1.y) + p2.y) + p3.y),
                   (((p0.z + p1.z) + p2.z) + p3.z),
                   (((p0.w + p1.w) + p2.w) + p3.w)};
    float ba[4] = {bv.x, bv.y, bv.z, bv.w};
    float sa[4] = {sv.x, sv.y, sv.z, sv.w};
    float aa[4] = {av.x, av.y, av.z, av.w};
    float ma[4] = {mv.x, mv.y, mv.z, mv.w};
    float fa[4] = {fv.x, fv.y, fv.z, fv.w};
    float ua[4] = {uv.x, uv.y, uv.z, uv.w};
    float mo[4], ao[4], uo[4], so[4];
#pragma unroll
    for (int j = 0; j < 4; j++) {
        float memr  = cr[j] + ba[j];      // rounded add
        float sp    = sa[j];
        float t1    = aa[j] * 0.9f;       // rounded
        float t2    = 0.5f * sp;          // exact
        float athn  = t1 + t2;            // rounded
        float u1    = ma[j] * 0.2f;       // rounded
        float u2    = 1.0f - sp;          // exact {1,0,-1}
        float u3    = u1 * u2;            // exact (sign/zero)
        float u4    = u3 + fa[j];         // rounded
        float u5    = athn * 0.2f;        // rounded
        float memff = u4 - u5;            // rounded
        float s_ff  = (memff > 0.5f) ? 1.0f : 0.0f;
        float s_r   = (memr  > 0.5f) ? 1.0f : 0.0f;
        mo[j] = memff + memr;             // rounded
        ao[j] = athn;
        so[j] = s_ff + s_r;               // exact
        uo[j] = ua[j] + so[j];            // exact (small ints)
    }
    *(float4*)(mem + base)     = make_float4(mo[0], mo[1], mo[2], mo[3]);
    *(float4*)(ath + base)     = make_float4(ao[0], ao[1], ao[2], ao[3]);
    *(float4*)(ssum + base)    = make_float4(uo[0], uo[1], uo[2], uo[3]);
    *(float4*)(spk_out + base) = make_float4(so[0], so[1], so[2], so[3]);
    if (last)
        *(float4*)(out + base) = make_float4(uo[0], uo[1], uo[2], uo[3]);
}

extern "C" void kernel_launch(void* const* d_in, const int* in_sizes, int n_in,
                              void* d_out, int out_size, void* d_ws, size_t ws_size,
                              hipStream_t stream) {
    const float* x      = (const float*)d_in[0];
    const float* W_fc   = (const float*)d_in[1];
    const float* b_fc   = (const float*)d_in[2];
    const float* W_rec  = (const float*)d_in[3];
    const float* b_rec  = (const float*)d_in[4];
    const int*   rmask  = (const int*)d_in[5];
    // d_in[6] = spike_window (16)

    char* ws = (char*)d_ws;
    float* WT   = (float*)(ws);                    // 16 MB (fc, then rec)
    float* ff   = (float*)(ws + (16u << 20));      //  4 MB
    float* mem  = (float*)(ws + (20u << 20));      //  4 MB
    float* ath  = (float*)(ws + (24u << 20));      //  4 MB
    float* ssum = (float*)(ws + (28u << 20));      //  4 MB
    float* spkA = (float*)(ws + (32u << 20));      //  4 MB
    float* spkB = (float*)(ws + (36u << 20));      //  4 MB
    float* Cp   = (float*)(ws + (40u << 20));      // 16 MB (total 56 MB)

    dim3 gridT(K_IN / 32, N_OUT / 32);             // (64, 64)
    dim3 blkT(32, 8);
    dim3 gridS((B_ROWS * N_OUT) / 256);            // 4096
    dim3 gridG(N_OUT / BTN, B_ROWS / BTM, NPANEL); // (16, 8, 4) = 512 blocks
    dim3 gridF((B_ROWS * N_OUT) / (256 * 4));      // 1024

    transpose_tile<<<gridT, blkT, 0, stream>>>(W_fc, rmask, WT, 0);
    init_state<<<gridS, 256, 0, stream>>>(mem, ath, ssum, spkA);
    gemm_panel<<<gridG, 128, 0, stream>>>(x, WT, Cp);
    ff_fold<<<gridF, 256, 0, stream>>>(Cp, b_fc, ff);
    transpose_tile<<<gridT, blkT, 0, stream>>>(W_rec, rmask, WT, 1);

    for (int t = 0; t < NSTEP; t++) {
        const float* si = (t & 1) ? spkB : spkA;
        float*       so = (t & 1) ? spkA : spkB;
        gemm_panel<<<gridG, 128, 0, stream>>>(si, WT, Cp);
        fold_update<<<gridF, 256, 0, stream>>>(
            Cp, b_rec, si, ff, mem, ath, ssum, so, (float*)d_out, t == NSTEP - 1);
    }
}